// Round 3
// baseline (195.984 us; speedup 1.0000x reference)
//
#include <hip/hip_runtime.h>

#define T_LEN 512
#define NHID 16
#define NEMB 10
#define VOCAB1 50001

typedef float v2f __attribute__((ext_vector_type(2)));

// ---------------------------------------------------------------------------
// Kernel 1: xproj table, layout [v][hi][j][2] f32 (64 floats per token).
//   float2 at (v*32 + hi*16 + j) = { gate(2*hi) , gate(2*hi+1) } for unit j,
//   gate q row r = q*16+j, value = bih[r]+bhh[r] + emb[v]·Wih[r].
// ---------------------------------------------------------------------------
__global__ __launch_bounds__(256) void build_table(
    const float* __restrict__ emb, const float* __restrict__ Wih,
    const float* __restrict__ bih, const float* __restrict__ bhh,
    float* __restrict__ tbl)
{
    const int tid = blockIdx.x * 256 + threadIdx.x;
    if (tid >= VOCAB1 * 16) return;
    const int v = tid >> 4, j = tid & 15;
    float e[NEMB];
    #pragma unroll
    for (int i = 0; i < NEMB; ++i) e[i] = emb[v * NEMB + i];
    float o[4];
    #pragma unroll
    for (int q = 0; q < 4; ++q) {
        const int r = q * 16 + j;
        float a = bih[r] + bhh[r];
        #pragma unroll
        for (int i = 0; i < NEMB; ++i) a += e[i] * Wih[r * NEMB + i];
        o[q] = a;
    }
    float2* t2 = (float2*)tbl;
    t2[v * 32 + j]      = make_float2(o[0], o[1]);   // i, f
    t2[v * 32 + 16 + j] = make_float2(o[2], o[3]);   // g, o
}

// ---------------------------------------------------------------------------
// Kernel 2: 32 lanes per batch -> 2048 waves (2/SIMD). Lane (hi,j):
//   hi=0 computes gate rows i,f for unit j; hi=1 computes g,o.
//   Cross-half swap: 2x shfl_xor(16). Both halves then hold identical
//   (i,f,g,o) -> bit-identical c/h, so the LDS h-broadcast (1 ds_write +
//   4 ds_read_b128, same-wave) is duplicate-value-safe.
//   Table loads pipelined 2 deep; idx read 3 ahead from LDS.
// ---------------------------------------------------------------------------
__global__ __launch_bounds__(256) void lstm32_kernel(
    const int*   __restrict__ x,
    const float* __restrict__ tbl,
    const float* __restrict__ Whh,
    const float* __restrict__ Wfc,
    const float* __restrict__ bfc,
    float*       __restrict__ out)
{
    __shared__ int   idx_lds[T_LEN][8];   // [t][local_batch] 16 KB
    __shared__ float hx[8 * 16];          // per-batch h exchange

    const int tid  = threadIdx.x;
    const int lane = tid & 63;
    const int j    = lane & 15;
    const int hi   = (lane >> 4) & 1;
    const int lb   = tid >> 5;            // local batch 0..7
    const int batch = blockIdx.x * 8 + lb;

    for (int i = tid; i < 8 * T_LEN; i += 256) {
        int b = i >> 9;
        int t = i & (T_LEN - 1);
        idx_lds[t][b] = x[(blockIdx.x * 8 + b) * T_LEN + t];
    }

    // recurrent weights: rows rA = (2*hi)*16+j, rB = rA+16, as float2 pairs
    v2f wA[8], wB[8];
    {
        const int rA = (2 * hi) * 16 + j;
        const int rB = rA + 16;
        #pragma unroll
        for (int p = 0; p < 8; ++p) {
            wA[p] = (v2f){Whh[rA * NHID + 2 * p], Whh[rA * NHID + 2 * p + 1]};
            wB[p] = (v2f){Whh[rB * NHID + 2 * p], Whh[rB * NHID + 2 * p + 1]};
        }
    }

    __syncthreads();

    v2f h2[8];
    #pragma unroll
    for (int p = 0; p < 8; ++p) h2[p] = (v2f){0.f, 0.f};
    float c = 0.f;

    const float NL2E  = -1.44269504088896f;
    const float NL2E2 = -2.88539008177793f;
    const bool  hib = (hi != 0);
    const float sA = hib ? NL2E2 : NL2E;  // tanh pre-scale for g, sigmoid for i
    const float mA = hib ? 2.f : 1.f;
    const float bA = hib ? -1.f : 0.f;

    const float2* tf2 = (const float2*)tbl;
    const int foff = hi * 16 + j;
    const float4* hp = (const float4*)&hx[lb * 16];

    // software pipeline: tb0 = row for t, tb1 = t+1 (in flight), i2 = idx[t+2]
    float2 tb0 = tf2[(long)idx_lds[0][lb] * 32 + foff];
    float2 tb1 = tf2[(long)idx_lds[1][lb] * 32 + foff];
    int    i2  = idx_lds[2][lb];

    #pragma unroll 1
    for (int t = 0; t < T_LEN; ++t) {
        // issue load for t+2 (2-deep: covers L2-miss/L3 latency)
        float2 tb2 = make_float2(0.f, 0.f);
        if (t + 2 < T_LEN) tb2 = tf2[(long)i2 * 32 + foff];
        const int i3 = (t + 3 < T_LEN) ? idx_lds[t + 3][lb] : 0;

        // two gate pre-activations (A = i or g, B = f or o)
        v2f aA = (v2f){tb0.x, 0.f}, aB = (v2f){tb0.y, 0.f};
        #pragma unroll
        for (int p = 0; p < 8; ++p) {
            aA += h2[p] * wA[p];
            aB += h2[p] * wB[p];
        }
        const float vA = aA.x + aA.y, vB = aB.x + aB.y;

        // gA: sigmoid (hi=0) or tanh (hi=1) via fused scale; gB: sigmoid
        const float gA = __builtin_amdgcn_rcpf(1.f + __builtin_amdgcn_exp2f(vA * sA)) * mA + bA;
        const float gB = __builtin_amdgcn_rcpf(1.f + __builtin_amdgcn_exp2f(vB * NL2E));

        // swap with the other half: half0 gets (g,o), half1 gets (i,f)
        const float othA = __shfl_xor(gA, 16, 64);
        const float othB = __shfl_xor(gB, 16, 64);

        const float ii = hib ? othA : gA;
        const float ff = hib ? othB : gB;
        const float gg = hib ? gA : othA;
        const float oo = hib ? gB : othB;

        c = ff * c + ii * gg;
        const float tc = 2.f * __builtin_amdgcn_rcpf(1.f + __builtin_amdgcn_exp2f(c * NL2E2)) - 1.f;
        const float hv = oo * tc;

        // h broadcast: both halves write identical bits to hx[lb*16+j]
        hx[lb * 16 + j] = hv;
        const float4 b0 = hp[0], b1 = hp[1], b2 = hp[2], b3 = hp[3];
        h2[0] = (v2f){b0.x, b0.y}; h2[1] = (v2f){b0.z, b0.w};
        h2[2] = (v2f){b1.x, b1.y}; h2[3] = (v2f){b1.z, b1.w};
        h2[4] = (v2f){b2.x, b2.y}; h2[5] = (v2f){b2.z, b2.w};
        h2[6] = (v2f){b3.x, b3.y}; h2[7] = (v2f){b3.z, b3.w};

        tb0 = tb1; tb1 = tb2; i2 = i3;
    }

    if ((lane & 31) == 0) {
        float logit = bfc[0];
        #pragma unroll
        for (int p = 0; p < 8; ++p)
            logit += h2[p].x * Wfc[2 * p] + h2[p].y * Wfc[2 * p + 1];
        out[batch] = __builtin_amdgcn_rcpf(1.f + __builtin_amdgcn_exp2f(logit * NL2E));
    }
}

// ---------------------------------------------------------------------------
// Fallback (ws too small for the 12.8 MB table): R2's 16-lane on-the-fly path.
// ---------------------------------------------------------------------------
__global__ __launch_bounds__(256) void lstm_fb_kernel(
    const int*   __restrict__ x,
    const float* __restrict__ emb,
    const float* __restrict__ Wih,
    const float* __restrict__ Whh,
    const float* __restrict__ bih,
    const float* __restrict__ bhh,
    const float* __restrict__ Wfc,
    const float* __restrict__ bfc,
    float*       __restrict__ out)
{
    __shared__ int   idx_lds[T_LEN][16];
    __shared__ float hx[4 * 64];

    const int tid  = threadIdx.x;
    const int wv   = tid >> 6;
    const int lane = tid & 63;
    const int j    = lane & 15;
    const int g    = lane >> 4;
    const int lb   = tid >> 4;
    const int batch = blockIdx.x * 16 + lb;

    for (int i = tid; i < 16 * T_LEN; i += 256) {
        int b = i >> 9;
        int t = i & (T_LEN - 1);
        idx_lds[t][b] = x[(blockIdx.x * 16 + b) * T_LEN + t];
    }

    float wih[4][NEMB], bias[4];
    v2f w[4][8];
    #pragma unroll
    for (int q = 0; q < 4; ++q) {
        const int r = j + 16 * q;
        #pragma unroll
        for (int e = 0; e < NEMB; ++e) wih[q][e] = Wih[r * NEMB + e];
        #pragma unroll
        for (int p = 0; p < 8; ++p)
            w[q][p] = (v2f){Whh[r * NHID + 2 * p], Whh[r * NHID + 2 * p + 1]};
        bias[q] = bih[r] + bhh[r];
    }

    __syncthreads();

    v2f h2[8];
    #pragma unroll
    for (int p = 0; p < 8; ++p) h2[p] = (v2f){0.f, 0.f};
    float c = 0.f;

    const float NL2E  = -1.44269504088896f;
    const float NL2E2 = -2.88539008177793f;
    const int hxW = wv * 64;
    const float4* hp = (const float4*)&hx[hxW + g * 16];

    float2 xa, xb, xc, xd, xe2;
    {
        const float2* er = (const float2*)(emb + (long)idx_lds[0][lb] * NEMB);
        xa = er[0]; xb = er[1]; xc = er[2]; xd = er[3]; xe2 = er[4];
    }
    int idx_n = idx_lds[1][lb];

    #pragma unroll 1
    for (int t = 0; t < T_LEN; ++t) {
        const float xv[NEMB] = {xa.x, xa.y, xb.x, xb.y, xc.x, xc.y,
                                xd.x, xd.y, xe2.x, xe2.y};
        if (t + 1 < T_LEN) {
            const float2* er = (const float2*)(emb + (long)idx_n * NEMB);
            xa = er[0]; xb = er[1]; xc = er[2]; xd = er[3]; xe2 = er[4];
        }
        const int idx_nn = (t + 2 < T_LEN) ? idx_lds[t + 2][lb] : 0;

        float v[4];
        #pragma unroll
        for (int q = 0; q < 4; ++q) {
            float a = bias[q];
            #pragma unroll
            for (int e = 0; e < NEMB; ++e) a += xv[e] * wih[q][e];
            v[q] = a;
        }
        v2f a0 = (v2f){v[0], 0.f}, a1 = (v2f){v[1], 0.f};
        v2f a2 = (v2f){v[2], 0.f}, a3 = (v2f){v[3], 0.f};
        #pragma unroll
        for (int p = 0; p < 8; ++p) {
            a0 += h2[p] * w[0][p];
            a1 += h2[p] * w[1][p];
            a2 += h2[p] * w[2][p];
            a3 += h2[p] * w[3][p];
        }
        const float vi = a0.x + a0.y, vf = a1.x + a1.y;
        const float vg = a2.x + a2.y, vo = a3.x + a3.y;

        const float ig = __builtin_amdgcn_rcpf(1.f + __builtin_amdgcn_exp2f(vi * NL2E));
        const float fg = __builtin_amdgcn_rcpf(1.f + __builtin_amdgcn_exp2f(vf * NL2E));
        const float gg = 2.f * __builtin_amdgcn_rcpf(1.f + __builtin_amdgcn_exp2f(vg * NL2E2)) - 1.f;
        const float og = __builtin_amdgcn_rcpf(1.f + __builtin_amdgcn_exp2f(vo * NL2E));

        c = fg * c + ig * gg;
        const float tc = 2.f * __builtin_amdgcn_rcpf(1.f + __builtin_amdgcn_exp2f(c * NL2E2)) - 1.f;
        const float hv = og * tc;

        hx[hxW + lane] = hv;
        const float4 b0 = hp[0], b1 = hp[1], b2 = hp[2], b3 = hp[3];
        h2[0] = (v2f){b0.x, b0.y}; h2[1] = (v2f){b0.z, b0.w};
        h2[2] = (v2f){b1.x, b1.y}; h2[3] = (v2f){b1.z, b1.w};
        h2[4] = (v2f){b2.x, b2.y}; h2[5] = (v2f){b2.z, b2.w};
        h2[6] = (v2f){b3.x, b3.y}; h2[7] = (v2f){b3.z, b3.w};

        idx_n = idx_nn;
    }

    if (j == 0) {
        float logit = bfc[0];
        #pragma unroll
        for (int p = 0; p < 8; ++p)
            logit += h2[p].x * Wfc[2 * p] + h2[p].y * Wfc[2 * p + 1];
        out[batch] = __builtin_amdgcn_rcpf(1.f + __builtin_amdgcn_exp2f(logit * NL2E));
    }
}

extern "C" void kernel_launch(void* const* d_in, const int* in_sizes, int n_in,
                              void* d_out, int out_size, void* d_ws, size_t ws_size,
                              hipStream_t stream) {
    const int*   x   = (const int*)  d_in[0];
    const float* emb = (const float*)d_in[1];
    const float* Wih = (const float*)d_in[2];
    const float* Whh = (const float*)d_in[3];
    const float* bih = (const float*)d_in[4];
    const float* bhh = (const float*)d_in[5];
    const float* Wfc = (const float*)d_in[6];
    const float* bfc = (const float*)d_in[7];
    float* outp = (float*)d_out;

    const int B = in_sizes[0] / T_LEN;                               // 4096
    const size_t TABLE_BYTES = (size_t)VOCAB1 * 64 * sizeof(float);  // 12.8 MB

    if (ws_size >= TABLE_BYTES) {
        float* tbl = (float*)d_ws;
        build_table<<<(VOCAB1 * 16 + 255) / 256, 256, 0, stream>>>(emb, Wih, bih, bhh, tbl);
        lstm32_kernel<<<B / 8, 256, 0, stream>>>(x, tbl, Whh, Wfc, bfc, outp);
    } else {
        lstm_fb_kernel<<<B / 16, 256, 0, stream>>>(x, emb, Wih, Whh, bih, bhh, Wfc, bfc, outp);
    }
}